// Round 9
// baseline (258.732 us; speedup 1.0000x reference)
//
#include <hip/hip_runtime.h>
#include <math.h>

#define NFILT 64
#define FRAME_STEP 160
#define WMAX 24            // max nonzero span of one mel filter (verified R1-R8)
#define WSTRIDE 25         // gcd(25,32)=1 -> conflict-free lane-indexed LDS reads
#define WAVES 4
#define NBLOCKS 6250       // 25000 waves -> exactly ONE pair per wave
#define PWBINS 280         // 257 bins + pad so the mel window can overrun

// One wave computes TWO frames (z = a + i*b through one 512-pt FFT).
// R3-verified structure; only the work distribution (1 pair/wave, 6250 blocks)
// and fast-intrinsic twiddle setup differ. Rationale: cross-round data shows
// duration tracks resident waves (R1: 90% occ / 58% VALUBusy at 50k blocks),
// not per-pair instruction count -- so maximize residency, minimize per-wave
// serial work.
__global__ __launch_bounds__(256) void fbank_kernel(const float* __restrict__ x,
                                                    const float* __restrict__ filters,
                                                    float* __restrict__ out,
                                                    int num_frames) {
    __shared__ float wc_lds[NFILT * WSTRIDE];
    __shared__ int   lo_lds[NFILT];
    __shared__ float pw[WAVES][PWBINS * 2];   // interleaved (pa, pb) per bin

    const int t = threadIdx.x;
    const int l = t & 63;              // lane
    const int w = t >> 6;              // wave in block
    float* pwrow = pw[w];

    // zero this wave's pad bins [257, PWBINS) once; never rewritten
    if (l < 2 * (PWBINS - 257)) pwrow[2 * 257 + l] = 0.0f;

    // ---- wave 0: batched filter-window scan (R4/R6-verified) ----
    if (w == 0) {
        int lo = 257;
#pragma unroll 4
        for (int k0 = 0; k0 < 264; k0 += 8) {
            float fv[8];
#pragma unroll
            for (int i = 0; i < 8; i++) {
                int k = k0 + i;
                fv[i] = (k < 257) ? filters[k * NFILT + l] : 0.0f;
            }
#pragma unroll
            for (int i = 0; i < 8; i++) {
                if (fv[i] != 0.0f && lo == 257) lo = k0 + i;
            }
        }
        if (lo > 256) lo = 256;
        lo_lds[l] = lo;
        for (int i = 0; i < WMAX; i++) {
            int k = lo + i;
            wc_lds[l * WSTRIDE + i] = (k <= 256) ? filters[k * NFILT + l] : 0.0f;
        }
    }

    // ---- loop-invariant twiddles (fast HW trig; error ~1e-6, invisible vs
    //      the 0.0156 bf16-rounding absmax floor) ----
    const int rl = (int)(__brev((unsigned)l) >> 26);    // rev6(lane) = k1
    float cA[6], sA[6], sg[6];
#pragma unroll
    for (int j = 0; j < 6; j++) {
        const int d = 32 >> j;
        const int hi = l & d;
        float th = -2.0f * (float)M_PI * (float)(l & (d - 1)) / (float)(2 * d);
        cA[j] = hi ? __cosf(th) : 1.0f;
        sA[j] = hi ? __sinf(th) : 0.0f;
        sg[j] = hi ? -1.0f : 1.0f;
    }
    float br[8], bi[8];                 // W_512^{n2*k1}
    {
        float th = -2.0f * (float)M_PI * (float)rl * (1.0f / 512.0f);
        float c1 = __cosf(th), s1 = __sinf(th);
        br[0] = 1.0f; bi[0] = 0.0f; br[1] = c1; bi[1] = s1;
#pragma unroll
        for (int r = 2; r < 8; r++) {
            float pr_ = br[r - 1], pi_ = bi[r - 1];
            br[r] = pr_ * c1 - pi_ * s1;
            bi[r] = pr_ * s1 + pi_ * c1;
        }
    }
    // conj partner lane: holds rl' = (64 - rl) & 63
    const int Lp = (int)(__brev((unsigned)((64 - rl) & 63)) >> 26);

    __syncthreads();
    const int lo = lo_lds[l];

    const int gw = blockIdx.x * WAVES + w;
    const int totw = NBLOCKS * WAVES;          // 25000
    const int npairs = (num_frames + 1) >> 1;  // 25000

    for (int pair = gw; pair < npairs; pair += totw) {   // executes once per wave
        const long fa = 2L * pair;
        const bool hasb = (fa + 1) < num_frames;
        const long ba = fa * FRAME_STEP;
        const long bb = ba + FRAME_STEP;

        // ---- load + pre-emphasis: frame a -> vr, frame b -> vi ----
        float vr[8], vi[8];
        {
            float a0=0,a1=0,a2=0,a3=0,a4=0,a5=0,a6=0,a7=0;
            if (l < 50) {
                const float4* p4 = reinterpret_cast<const float4*>(x + ba + 8 * l);
                float4 A = p4[0], B = p4[1];
                a0=A.x; a1=A.y; a2=A.z; a3=A.w; a4=B.x; a5=B.y; a6=B.z; a7=B.w;
            }
            float ev = x[ba > 0 ? ba - 1 : 0];
            float edge = (ba > 0) ? ev : 0.0f;     // pre[0] = x[0] - 0.97*0
            float prev = __shfl_up(a7, 1, 64);
            if (l == 0) prev = edge;
            vr[0] = (l < 50) ? fmaf(-0.97f, prev, a0) : 0.0f;
            vr[1] = (l < 50) ? fmaf(-0.97f, a0, a1) : 0.0f;
            vr[2] = (l < 50) ? fmaf(-0.97f, a1, a2) : 0.0f;
            vr[3] = (l < 50) ? fmaf(-0.97f, a2, a3) : 0.0f;
            vr[4] = (l < 50) ? fmaf(-0.97f, a3, a4) : 0.0f;
            vr[5] = (l < 50) ? fmaf(-0.97f, a4, a5) : 0.0f;
            vr[6] = (l < 50) ? fmaf(-0.97f, a5, a6) : 0.0f;
            vr[7] = (l < 50) ? fmaf(-0.97f, a6, a7) : 0.0f;
        }
        {
            float b0=0,b1=0,b2=0,b3=0,b4=0,b5=0,b6=0,b7=0;
            if (hasb && l < 50) {
                const float4* p4 = reinterpret_cast<const float4*>(x + bb + 8 * l);
                float4 A = p4[0], B = p4[1];
                b0=A.x; b1=A.y; b2=A.z; b3=A.w; b4=B.x; b5=B.y; b6=B.z; b7=B.w;
            }
            float edge = hasb ? x[bb - 1] : 0.0f;  // bb >= 160 always
            float prev = __shfl_up(b7, 1, 64);
            if (l == 0) prev = edge;
            vi[0] = (l < 50) ? fmaf(-0.97f, prev, b0) : 0.0f;
            vi[1] = (l < 50) ? fmaf(-0.97f, b0, b1) : 0.0f;
            vi[2] = (l < 50) ? fmaf(-0.97f, b1, b2) : 0.0f;
            vi[3] = (l < 50) ? fmaf(-0.97f, b2, b3) : 0.0f;
            vi[4] = (l < 50) ? fmaf(-0.97f, b3, b4) : 0.0f;
            vi[5] = (l < 50) ? fmaf(-0.97f, b4, b5) : 0.0f;
            vi[6] = (l < 50) ? fmaf(-0.97f, b5, b6) : 0.0f;
            vi[7] = (l < 50) ? fmaf(-0.97f, b6, b7) : 0.0f;
        }

        // ---- cross-lane 64-pt DIF FFT (6 shuffle stages, complex) ----
#pragma unroll
        for (int j = 0; j < 6; j++) {
            const int d = 32 >> j;
            const float c = cA[j], s = sA[j], g = sg[j];
#pragma unroll
            for (int r = 0; r < 8; r++) {
                float pr = __shfl_xor(vr[r], d, 64);
                float pi = __shfl_xor(vi[r], d, 64);
                float tr = fmaf(g, vr[r], pr);
                float ti = fmaf(g, vi[r], pi);
                vr[r] = tr * c - ti * s;
                vi[r] = tr * s + ti * c;
            }
        }
        // lane l holds A[k1 = rev6(l)] per sample-group n2 = r

        // ---- twiddle W_512^{n2*k1} ----
#pragma unroll
        for (int r = 1; r < 8; r++) {
            float tr = vr[r], ti = vi[r];
            vr[r] = tr * br[r] - ti * bi[r];
            vi[r] = tr * bi[r] + ti * br[r];
        }

        // ---- in-register 8-pt DIF FFT over n2 ----
        const float RH = 0.70710678118654752f;
        {
            float t0r=vr[0]+vr[4], t0i=vi[0]+vi[4];
            float d0r=vr[0]-vr[4], d0i=vi[0]-vi[4];
            float t1r=vr[1]+vr[5], t1i=vi[1]+vi[5];
            float d1r=vr[1]-vr[5], d1i=vi[1]-vi[5];
            float t2r=vr[2]+vr[6], t2i=vi[2]+vi[6];
            float d2r=vr[2]-vr[6], d2i=vi[2]-vi[6];
            float t3r=vr[3]+vr[7], t3i=vi[3]+vi[7];
            float d3r=vr[3]-vr[7], d3i=vi[3]-vi[7];
            vr[0]=t0r; vi[0]=t0i; vr[1]=t1r; vi[1]=t1i;
            vr[2]=t2r; vi[2]=t2i; vr[3]=t3r; vi[3]=t3i;
            vr[4]=d0r;                 vi[4]=d0i;
            vr[5]=(d1r+d1i)*RH;        vi[5]=(d1i-d1r)*RH;
            vr[6]=d2i;                 vi[6]=-d2r;
            vr[7]=(d3i-d3r)*RH;        vi[7]=-(d3r+d3i)*RH;
        }
        {
            float t0r=vr[0]+vr[2], t0i=vi[0]+vi[2];
            float d0r=vr[0]-vr[2], d0i=vi[0]-vi[2];
            float t1r=vr[1]+vr[3], t1i=vi[1]+vi[3];
            float d1r=vr[1]-vr[3], d1i=vi[1]-vi[3];
            vr[0]=t0r; vi[0]=t0i; vr[1]=t1r; vi[1]=t1i;
            vr[2]=d0r; vi[2]=d0i; vr[3]=d1i; vi[3]=-d1r;
            float t4r=vr[4]+vr[6], t4i=vi[4]+vi[6];
            float d4r=vr[4]-vr[6], d4i=vi[4]-vi[6];
            float t5r=vr[5]+vr[7], t5i=vi[5]+vi[7];
            float d5r=vr[5]-vr[7], d5i=vi[5]-vi[7];
            vr[4]=t4r; vi[4]=t4i; vr[5]=t5r; vi[5]=t5i;
            vr[6]=d4r; vi[6]=d4i; vr[7]=d5i; vi[7]=-d5r;
        }
        {
            float t0r=vr[0]+vr[1], t0i=vi[0]+vi[1];
            float d0r=vr[0]-vr[1], d0i=vi[0]-vi[1];
            vr[0]=t0r; vi[0]=t0i; vr[1]=d0r; vi[1]=d0i;
            float t2r=vr[2]+vr[3], t2i=vi[2]+vi[3];
            float d2r=vr[2]-vr[3], d2i=vi[2]-vi[3];
            vr[2]=t2r; vi[2]=t2i; vr[3]=d2r; vi[3]=d2i;
            float t4r=vr[4]+vr[5], t4i=vi[4]+vi[5];
            float d4r=vr[4]-vr[5], d4i=vi[4]-vi[5];
            vr[4]=t4r; vi[4]=t4i; vr[5]=d4r; vi[5]=d4i;
            float t6r=vr[6]+vr[7], t6i=vi[6]+vi[7];
            float d6r=vr[6]-vr[7], d6i=vi[6]-vi[7];
            vr[6]=t6r; vi[6]=t6i; vr[7]=d6r; vi[7]=d6i;
        }
        // reg p holds Z[rev6(l) + 64*rev3(p)]; needed bins: k2=0..3 in p={0,4,2,6},
        // plus bin 256 = lane 0's p=1.

        // ---- conjugate-symmetry untangle: Zc[k] = conj(Z[512-k]) ----
        float c0r = __shfl(vr[7], Lp, 64), c0i = __shfl(vi[7], Lp, 64);  // p=0
        float c1r = __shfl(vr[3], Lp, 64), c1i = __shfl(vi[3], Lp, 64);  // p=4
        float c2r = __shfl(vr[5], Lp, 64), c2i = __shfl(vi[5], Lp, 64);  // p=2
        float c3r = __shfl(vr[1], Lp, 64), c3i = __shfl(vi[1], Lp, 64);  // p=6
        if (l == 0) {
            c0r = vr[0]; c0i = vi[0];   // bin 0   <- Z[0]
            c1r = vr[7]; c1i = vi[7];   // bin 64  <- Z[448]
            c2r = vr[3]; c2i = vi[3];   // bin 128 <- Z[384]
            c3r = vr[5]; c3i = vi[5];   // bin 192 <- Z[320]
        }

        // ---- untangle + power -> LDS (interleaved a,b) ----
        const float S4 = (1.0f / 512.0f) * 0.25f;
        {
            float zr = vr[0], zi = vi[0];
            float e1 = zr + c0r, e2 = zi - c0i, o1 = zi + c0i, o2 = c0r - zr;
            *reinterpret_cast<float2*>(&pwrow[2 * rl]) =
                make_float2((e1*e1 + e2*e2) * S4, (o1*o1 + o2*o2) * S4);
        }
        {
            float zr = vr[4], zi = vi[4];
            float e1 = zr + c1r, e2 = zi - c1i, o1 = zi + c1i, o2 = c1r - zr;
            *reinterpret_cast<float2*>(&pwrow[2 * (rl + 64)]) =
                make_float2((e1*e1 + e2*e2) * S4, (o1*o1 + o2*o2) * S4);
        }
        {
            float zr = vr[2], zi = vi[2];
            float e1 = zr + c2r, e2 = zi - c2i, o1 = zi + c2i, o2 = c2r - zr;
            *reinterpret_cast<float2*>(&pwrow[2 * (rl + 128)]) =
                make_float2((e1*e1 + e2*e2) * S4, (o1*o1 + o2*o2) * S4);
        }
        {
            float zr = vr[6], zi = vi[6];
            float e1 = zr + c3r, e2 = zi - c3i, o1 = zi + c3i, o2 = c3r - zr;
            *reinterpret_cast<float2*>(&pwrow[2 * (rl + 192)]) =
                make_float2((e1*e1 + e2*e2) * S4, (o1*o1 + o2*o2) * S4);
        }
        if (l == 0) {   // bin 256 pairs with itself: Xa=Re(Z[256]), Xb=Im(Z[256])
            pwrow[512] = vr[1] * vr[1] * (1.0f / 512.0f);
            pwrow[513] = vi[1] * vi[1] * (1.0f / 512.0f);
        }

        asm volatile("s_waitcnt lgkmcnt(0)" ::: "memory");  // wave-local fence

        // ---- sparse mel matmul, both frames per ds_read_b64 ----
        float acca = 1e-30f, accb = 1e-30f;
#pragma unroll
        for (int i = 0; i < WMAX; i++) {
            float wv = wc_lds[l * WSTRIDE + i];
            float2 pq = *reinterpret_cast<const float2*>(&pwrow[2 * (lo + i)]);
            acca = fmaf(wv, pq.x, acca);
            accb = fmaf(wv, pq.y, accb);
        }

        // ---- per-frame normalize (independent chains, interleaved) ----
        float sa = acca, sb = accb;
#pragma unroll
        for (int mk = 1; mk < 64; mk <<= 1) {
            sa += __shfl_xor(sa, mk, 64);
            sb += __shfl_xor(sb, mk, 64);
        }
        const float ma = sa * (1.0f / 64.0f), mb = sb * (1.0f / 64.0f);
        const float da = acca - ma, db = accb - mb;
        float va = da * da, vb = db * db;
#pragma unroll
        for (int mk = 1; mk < 64; mk <<= 1) {
            va += __shfl_xor(va, mk, 64);
            vb += __shfl_xor(vb, mk, 64);
        }
        out[fa * NFILT + l] = da * rsqrtf(va * (1.0f / 64.0f));
        if (hasb)
            out[(fa + 1) * NFILT + l] = db * rsqrtf(vb * (1.0f / 64.0f));
    }
}

extern "C" void kernel_launch(void* const* d_in, const int* in_sizes, int n_in,
                              void* d_out, int out_size, void* d_ws, size_t ws_size,
                              hipStream_t stream) {
    (void)d_ws; (void)ws_size; (void)n_in; (void)in_sizes;
    const float* x = (const float*)d_in[0];
    const float* filters = (const float*)d_in[1];
    float* out = (float*)d_out;
    const int num_frames = out_size / NFILT;
    fbank_kernel<<<NBLOCKS, 256, 0, stream>>>(x, filters, out, num_frames);
}

// Round 10
// 136.539 us; speedup vs baseline: 1.8949x; 1.8949x over previous
//
#include <hip/hip_runtime.h>
#include <math.h>

#define NFILT 64
#define FRAME_STEP 160
#define WMAX 24            // max nonzero span of one mel filter (verified R1-R9)
#define WSTRIDE 25         // gcd(25,32)=1 -> conflict-free lane-indexed LDS reads
#define WAVES 4
#define NBLOCKS 1563       // 6252 waves x 4 pairs (R3-verified distribution)
#define PWBINS 280         // 257 bins + pad so the mel window can overrun

// R3-verified structure (102 us), with exactly two verified micro-deltas:
// batched filter scan (R4/R6) and fast HW trig setup + rsqrtf (R9).
__global__ __launch_bounds__(256) void fbank_kernel(const float* __restrict__ x,
                                                    const float* __restrict__ filters,
                                                    float* __restrict__ out,
                                                    int num_frames) {
    __shared__ float wc_lds[NFILT * WSTRIDE];
    __shared__ int   lo_lds[NFILT];
    __shared__ float pw[WAVES][PWBINS * 2];   // interleaved (pa, pb) per bin

    const int t = threadIdx.x;
    const int l = t & 63;              // lane
    const int w = t >> 6;              // wave in block
    float* pwrow = pw[w];

    // zero this wave's pad bins [257, PWBINS) once; never rewritten
    if (l < 2 * (PWBINS - 257)) pwrow[2 * 257 + l] = 0.0f;

    // ---- wave 0: batched filter-window scan (R4/R6-verified) ----
    if (w == 0) {
        int lo = 257;
#pragma unroll 4
        for (int k0 = 0; k0 < 264; k0 += 8) {
            float fv[8];
#pragma unroll
            for (int i = 0; i < 8; i++) {
                int k = k0 + i;
                fv[i] = (k < 257) ? filters[k * NFILT + l] : 0.0f;
            }
#pragma unroll
            for (int i = 0; i < 8; i++) {
                if (fv[i] != 0.0f && lo == 257) lo = k0 + i;   // cndmask chain only
            }
        }
        if (lo > 256) lo = 256;
        lo_lds[l] = lo;
        for (int i = 0; i < WMAX; i++) {
            int k = lo + i;
            wc_lds[l * WSTRIDE + i] = (k <= 256) ? filters[k * NFILT + l] : 0.0f;
        }
    }

    // ---- loop-invariant twiddles (HW trig, R9-verified: absmax unchanged) ----
    const int rl = (int)(__brev((unsigned)l) >> 26);    // rev6(lane) = k1
    float cA[6], sA[6], sg[6];
#pragma unroll
    for (int j = 0; j < 6; j++) {
        const int d = 32 >> j;
        const int hi = l & d;
        float th = -2.0f * (float)M_PI * (float)(l & (d - 1)) / (float)(2 * d);
        cA[j] = hi ? __cosf(th) : 1.0f;
        sA[j] = hi ? __sinf(th) : 0.0f;
        sg[j] = hi ? -1.0f : 1.0f;
    }
    float br[8], bi[8];                 // W_512^{n2*k1}
    {
        float th = -2.0f * (float)M_PI * (float)rl * (1.0f / 512.0f);
        float c1 = __cosf(th), s1 = __sinf(th);
        br[0] = 1.0f; bi[0] = 0.0f; br[1] = c1; bi[1] = s1;
#pragma unroll
        for (int r = 2; r < 8; r++) {
            float pr_ = br[r - 1], pi_ = bi[r - 1];
            br[r] = pr_ * c1 - pi_ * s1;
            bi[r] = pr_ * s1 + pi_ * c1;
        }
    }
    // conj partner lane: holds rl' = (64 - rl) & 63
    const int Lp = (int)(__brev((unsigned)((64 - rl) & 63)) >> 26);

    __syncthreads();
    const int lo = lo_lds[l];

    const int gw = blockIdx.x * WAVES + w;       // global wave id
    const int totw = NBLOCKS * WAVES;            // 6252
    const int npairs = (num_frames + 1) >> 1;

    for (int pair = gw; pair < npairs; pair += totw) {
        const long fa = 2L * pair;
        const bool hasb = (fa + 1) < num_frames;
        const long ba = fa * FRAME_STEP;
        const long bb = ba + FRAME_STEP;

        // ---- load + pre-emphasis: frame a -> vr, frame b -> vi ----
        float vr[8], vi[8];
        {
            float a0=0,a1=0,a2=0,a3=0,a4=0,a5=0,a6=0,a7=0;
            if (l < 50) {
                const float4* p4 = reinterpret_cast<const float4*>(x + ba + 8 * l);
                float4 A = p4[0], B = p4[1];
                a0=A.x; a1=A.y; a2=A.z; a3=A.w; a4=B.x; a5=B.y; a6=B.z; a7=B.w;
            }
            float ev = x[ba > 0 ? ba - 1 : 0];
            float edge = (ba > 0) ? ev : 0.0f;     // pre[0] = x[0] - 0.97*0
            float prev = __shfl_up(a7, 1, 64);
            if (l == 0) prev = edge;
            vr[0] = (l < 50) ? fmaf(-0.97f, prev, a0) : 0.0f;
            vr[1] = (l < 50) ? fmaf(-0.97f, a0, a1) : 0.0f;
            vr[2] = (l < 50) ? fmaf(-0.97f, a1, a2) : 0.0f;
            vr[3] = (l < 50) ? fmaf(-0.97f, a2, a3) : 0.0f;
            vr[4] = (l < 50) ? fmaf(-0.97f, a3, a4) : 0.0f;
            vr[5] = (l < 50) ? fmaf(-0.97f, a4, a5) : 0.0f;
            vr[6] = (l < 50) ? fmaf(-0.97f, a5, a6) : 0.0f;
            vr[7] = (l < 50) ? fmaf(-0.97f, a6, a7) : 0.0f;
        }
        {
            float b0=0,b1=0,b2=0,b3=0,b4=0,b5=0,b6=0,b7=0;
            if (hasb && l < 50) {
                const float4* p4 = reinterpret_cast<const float4*>(x + bb + 8 * l);
                float4 A = p4[0], B = p4[1];
                b0=A.x; b1=A.y; b2=A.z; b3=A.w; b4=B.x; b5=B.y; b6=B.z; b7=B.w;
            }
            float edge = hasb ? x[bb - 1] : 0.0f;  // bb >= 160 always
            float prev = __shfl_up(b7, 1, 64);
            if (l == 0) prev = edge;
            vi[0] = (l < 50) ? fmaf(-0.97f, prev, b0) : 0.0f;
            vi[1] = (l < 50) ? fmaf(-0.97f, b0, b1) : 0.0f;
            vi[2] = (l < 50) ? fmaf(-0.97f, b1, b2) : 0.0f;
            vi[3] = (l < 50) ? fmaf(-0.97f, b2, b3) : 0.0f;
            vi[4] = (l < 50) ? fmaf(-0.97f, b3, b4) : 0.0f;
            vi[5] = (l < 50) ? fmaf(-0.97f, b4, b5) : 0.0f;
            vi[6] = (l < 50) ? fmaf(-0.97f, b5, b6) : 0.0f;
            vi[7] = (l < 50) ? fmaf(-0.97f, b6, b7) : 0.0f;
        }

        // ---- cross-lane 64-pt DIF FFT (6 shuffle stages, complex) ----
#pragma unroll
        for (int j = 0; j < 6; j++) {
            const int d = 32 >> j;
            const float c = cA[j], s = sA[j], g = sg[j];
#pragma unroll
            for (int r = 0; r < 8; r++) {
                float pr = __shfl_xor(vr[r], d, 64);
                float pi = __shfl_xor(vi[r], d, 64);
                float tr = fmaf(g, vr[r], pr);
                float ti = fmaf(g, vi[r], pi);
                vr[r] = tr * c - ti * s;
                vi[r] = tr * s + ti * c;
            }
        }
        // lane l holds A[k1 = rev6(l)] per sample-group n2 = r

        // ---- twiddle W_512^{n2*k1} ----
#pragma unroll
        for (int r = 1; r < 8; r++) {
            float tr = vr[r], ti = vi[r];
            vr[r] = tr * br[r] - ti * bi[r];
            vi[r] = tr * bi[r] + ti * br[r];
        }

        // ---- in-register 8-pt DIF FFT over n2 ----
        const float RH = 0.70710678118654752f;
        {
            float t0r=vr[0]+vr[4], t0i=vi[0]+vi[4];
            float d0r=vr[0]-vr[4], d0i=vi[0]-vi[4];
            float t1r=vr[1]+vr[5], t1i=vi[1]+vi[5];
            float d1r=vr[1]-vr[5], d1i=vi[1]-vi[5];
            float t2r=vr[2]+vr[6], t2i=vi[2]+vi[6];
            float d2r=vr[2]-vr[6], d2i=vi[2]-vi[6];
            float t3r=vr[3]+vr[7], t3i=vi[3]+vi[7];
            float d3r=vr[3]-vr[7], d3i=vi[3]-vi[7];
            vr[0]=t0r; vi[0]=t0i; vr[1]=t1r; vi[1]=t1i;
            vr[2]=t2r; vi[2]=t2i; vr[3]=t3r; vi[3]=t3i;
            vr[4]=d0r;                 vi[4]=d0i;
            vr[5]=(d1r+d1i)*RH;        vi[5]=(d1i-d1r)*RH;
            vr[6]=d2i;                 vi[6]=-d2r;
            vr[7]=(d3i-d3r)*RH;        vi[7]=-(d3r+d3i)*RH;
        }
        {
            float t0r=vr[0]+vr[2], t0i=vi[0]+vi[2];
            float d0r=vr[0]-vr[2], d0i=vi[0]-vi[2];
            float t1r=vr[1]+vr[3], t1i=vi[1]+vi[3];
            float d1r=vr[1]-vr[3], d1i=vi[1]-vi[3];
            vr[0]=t0r; vi[0]=t0i; vr[1]=t1r; vi[1]=t1i;
            vr[2]=d0r; vi[2]=d0i; vr[3]=d1i; vi[3]=-d1r;
            float t4r=vr[4]+vr[6], t4i=vi[4]+vi[6];
            float d4r=vr[4]-vr[6], d4i=vi[4]-vi[6];
            float t5r=vr[5]+vr[7], t5i=vi[5]+vi[7];
            float d5r=vr[5]-vr[7], d5i=vi[5]-vi[7];
            vr[4]=t4r; vi[4]=t4i; vr[5]=t5r; vi[5]=t5i;
            vr[6]=d4r; vi[6]=d4i; vr[7]=d5i; vi[7]=-d5r;
        }
        {
            float t0r=vr[0]+vr[1], t0i=vi[0]+vi[1];
            float d0r=vr[0]-vr[1], d0i=vi[0]-vi[1];
            vr[0]=t0r; vi[0]=t0i; vr[1]=d0r; vi[1]=d0i;
            float t2r=vr[2]+vr[3], t2i=vi[2]+vi[3];
            float d2r=vr[2]-vr[3], d2i=vi[2]-vi[3];
            vr[2]=t2r; vi[2]=t2i; vr[3]=d2r; vi[3]=d2i;
            float t4r=vr[4]+vr[5], t4i=vi[4]+vi[5];
            float d4r=vr[4]-vr[5], d4i=vi[4]-vi[5];
            vr[4]=t4r; vi[4]=t4i; vr[5]=d4r; vi[5]=d4i;
            float t6r=vr[6]+vr[7], t6i=vi[6]+vi[7];
            float d6r=vr[6]-vr[7], d6i=vi[6]-vi[7];
            vr[6]=t6r; vi[6]=t6i; vr[7]=d6r; vi[7]=d6i;
        }
        // reg p holds Z[rev6(l) + 64*rev3(p)]; needed bins: k2=0..3 in p={0,4,2,6},
        // plus bin 256 = lane 0's p=1.

        // ---- conjugate-symmetry untangle: Zc[k] = conj(Z[512-k]) ----
        float c0r = __shfl(vr[7], Lp, 64), c0i = __shfl(vi[7], Lp, 64);  // p=0
        float c1r = __shfl(vr[3], Lp, 64), c1i = __shfl(vi[3], Lp, 64);  // p=4
        float c2r = __shfl(vr[5], Lp, 64), c2i = __shfl(vi[5], Lp, 64);  // p=2
        float c3r = __shfl(vr[1], Lp, 64), c3i = __shfl(vi[1], Lp, 64);  // p=6
        if (l == 0) {
            c0r = vr[0]; c0i = vi[0];   // bin 0   <- Z[0]
            c1r = vr[7]; c1i = vi[7];   // bin 64  <- Z[448]
            c2r = vr[3]; c2i = vi[3];   // bin 128 <- Z[384]
            c3r = vr[5]; c3i = vi[5];   // bin 192 <- Z[320]
        }

        // ---- untangle + power -> LDS (interleaved a,b) ----
        const float S4 = (1.0f / 512.0f) * 0.25f;
        {
            float zr = vr[0], zi = vi[0];
            float e1 = zr + c0r, e2 = zi - c0i, o1 = zi + c0i, o2 = c0r - zr;
            *reinterpret_cast<float2*>(&pwrow[2 * rl]) =
                make_float2((e1*e1 + e2*e2) * S4, (o1*o1 + o2*o2) * S4);
        }
        {
            float zr = vr[4], zi = vi[4];
            float e1 = zr + c1r, e2 = zi - c1i, o1 = zi + c1i, o2 = c1r - zr;
            *reinterpret_cast<float2*>(&pwrow[2 * (rl + 64)]) =
                make_float2((e1*e1 + e2*e2) * S4, (o1*o1 + o2*o2) * S4);
        }
        {
            float zr = vr[2], zi = vi[2];
            float e1 = zr + c2r, e2 = zi - c2i, o1 = zi + c2i, o2 = c2r - zr;
            *reinterpret_cast<float2*>(&pwrow[2 * (rl + 128)]) =
                make_float2((e1*e1 + e2*e2) * S4, (o1*o1 + o2*o2) * S4);
        }
        {
            float zr = vr[6], zi = vi[6];
            float e1 = zr + c3r, e2 = zi - c3i, o1 = zi + c3i, o2 = c3r - zr;
            *reinterpret_cast<float2*>(&pwrow[2 * (rl + 192)]) =
                make_float2((e1*e1 + e2*e2) * S4, (o1*o1 + o2*o2) * S4);
        }
        if (l == 0) {   // bin 256 pairs with itself: Xa=Re(Z[256]), Xb=Im(Z[256])
            pwrow[512] = vr[1] * vr[1] * (1.0f / 512.0f);
            pwrow[513] = vi[1] * vi[1] * (1.0f / 512.0f);
        }

        asm volatile("s_waitcnt lgkmcnt(0)" ::: "memory");  // wave-local fence

        // ---- sparse mel matmul, both frames per ds_read_b64 ----
        float acca = 1e-30f, accb = 1e-30f;
#pragma unroll
        for (int i = 0; i < WMAX; i++) {
            float wv = wc_lds[l * WSTRIDE + i];
            float2 pq = *reinterpret_cast<const float2*>(&pwrow[2 * (lo + i)]);
            acca = fmaf(wv, pq.x, acca);
            accb = fmaf(wv, pq.y, accb);
        }

        // ---- per-frame normalize (independent chains, interleaved) ----
        float sa = acca, sb = accb;
#pragma unroll
        for (int mk = 1; mk < 64; mk <<= 1) {
            sa += __shfl_xor(sa, mk, 64);
            sb += __shfl_xor(sb, mk, 64);
        }
        const float ma = sa * (1.0f / 64.0f), mb = sb * (1.0f / 64.0f);
        const float da = acca - ma, db = accb - mb;
        float va = da * da, vb = db * db;
#pragma unroll
        for (int mk = 1; mk < 64; mk <<= 1) {
            va += __shfl_xor(va, mk, 64);
            vb += __shfl_xor(vb, mk, 64);
        }
        out[fa * NFILT + l] = da * rsqrtf(va * (1.0f / 64.0f));
        if (hasb)
            out[(fa + 1) * NFILT + l] = db * rsqrtf(vb * (1.0f / 64.0f));
    }
}

extern "C" void kernel_launch(void* const* d_in, const int* in_sizes, int n_in,
                              void* d_out, int out_size, void* d_ws, size_t ws_size,
                              hipStream_t stream) {
    (void)d_ws; (void)ws_size; (void)n_in; (void)in_sizes;
    const float* x = (const float*)d_in[0];
    const float* filters = (const float*)d_in[1];
    float* out = (float*)d_out;
    const int num_frames = out_size / NFILT;
    fbank_kernel<<<NBLOCKS, 256, 0, stream>>>(x, filters, out, num_frames);
}